// Round 3
// baseline (6142.191 us; speedup 1.0000x reference)
//
#include <hip/hip_runtime.h>
#include <cstdint>

// ---------------------------------------------------------------------------
// Threefry-2x32 (JAX partitionable-mode compatible), host + device.
// ---------------------------------------------------------------------------
__host__ __device__ inline uint32_t tf_rotl32(uint32_t x, uint32_t r) {
  return (x << r) | (x >> (32u - r));
}

__host__ __device__ inline void threefry2x32(uint32_t k0, uint32_t k1,
                                             uint32_t x0, uint32_t x1,
                                             uint32_t* o0, uint32_t* o1) {
  uint32_t ks0 = k0, ks1 = k1, ks2 = k0 ^ k1 ^ 0x1BD11BDAu;
  x0 += ks0; x1 += ks1;
#define TF_R(r) { x0 += x1; x1 = tf_rotl32(x1, r); x1 ^= x0; }
  TF_R(13) TF_R(15) TF_R(26) TF_R(6)
  x0 += ks1; x1 += ks2 + 1u;
  TF_R(17) TF_R(29) TF_R(16) TF_R(24)
  x0 += ks2; x1 += ks0 + 2u;
  TF_R(13) TF_R(15) TF_R(26) TF_R(6)
  x0 += ks0; x1 += ks1 + 3u;
  TF_R(17) TF_R(29) TF_R(16) TF_R(24)
  x0 += ks1; x1 += ks2 + 4u;
  TF_R(13) TF_R(15) TF_R(26) TF_R(6)
  x0 += ks2; x1 += ks0 + 5u;
#undef TF_R
  *o0 = x0; *o1 = x1;
}

// ---------------------------------------------------------------------------
// Problem dims
// ---------------------------------------------------------------------------
#define BSZ   8192
#define KIN   784
#define HID   800
#define NOUT  10
#define NSTEP 25

// R8: golden = Eigen gebp (AVX no-FMA jaxlib): k-panels [0,264) [264,528)
// [528,784), per k-step acc = rn(acc + rn(a*b)).
// R9: a in {0,1,2} makes every product exact, so fmaf == mul+add bit-exactly.
//     (R0 post-mortem: compiler was already contracting — no delta.)
// R10: GEMM was LDS-READ-BW bound (1.0 B/FLOP -> 173us matches the
//     85-95 B/cyc/CU ds_read ceiling; VALUBusy 52% = the 65us FMA floor).
//     Fix: A stored as packed u8 in LDS (values {0,1,2}; byte->f32 converts
//     are (float)((x>>8i)&0xff) which LLVM folds to v_cvt_f32_ubyte_i) +
//     8x4 register tile -> 24B per 64 FLOP (0.375 B/FLOP). New bound: VALU
//     (32 FMA + 8 cvt)/kk ~ 83us floor.
// R11 (this round): compile fix only — no __builtin_amdgcn_cvt_f32_ubyteN
//     builtin exists; use the C idiom above.
// ---------------------------------------------------------------------------
#define PANEL1 264
#define PANEL2 528

// ---------------------------------------------------------------------------
// Kernel 1: Poisson encoding (JAX-faithful: truncated 2^-23 grid).
// enc = temp + 1 in {0,1,2}; sp = 0.5*enc (exact power-of-2 relation).
// ---------------------------------------------------------------------------
__global__ __launch_bounds__(256) void enc_kernel(const float* __restrict__ inp,
                                                  uint8_t* __restrict__ enc,
                                                  uint32_t k0, uint32_t k1) {
  int j = blockIdx.x * blockDim.x + threadIdx.x;
  if (j >= BSZ * KIN) return;
  uint32_t o0, o1;
  threefry2x32(k0, k1, 0u, (uint32_t)j, &o0, &o1);
  uint32_t bits = o0 ^ o1;
  float r = __uint_as_float((bits >> 9) | 0x3f800000u) - 1.0f;
  float x = inp[j];
  bool cond = (2.0f * r <= fabsf(x));
  int s = (x > 0.0f) ? 1 : ((x < 0.0f) ? -1 : 0);
  enc[j] = (uint8_t)(1 + (cond ? s : 0));
}

// ---------------------------------------------------------------------------
// Kernel 2: g[b,j] = 0.5 * ((P0 + P1) + P2), Eigen panels at k=264,528.
// BM=128, BN=32, BK=16. 128 threads (2 waves), 8x4 acc per thread.
// As: packed u8 [BK][BM] (u32-packed, 4 rows/word). Bs: f32 [BK][BN].
// Per kk: ds_read_b64 (8 u8 rows) + ds_read_b128 (4 f32 cols) per 64 FLOP.
// ---------------------------------------------------------------------------
#define BM 128
#define BN 32
#define BK 16

__device__ __forceinline__ float cvt_ub(uint32_t x, int i) {
  return (float)((x >> (8 * i)) & 0xffu);   // folds to v_cvt_f32_ubyte_i
}

__global__ __launch_bounds__(128) void gemm_kernel(const uint8_t* __restrict__ enc,
                                                   const float* __restrict__ w1,
                                                   float* __restrict__ g) {
  __shared__ uint32_t As[BK][BM / 4];  // byte i of word r: A[row 4r+i][col k] — 2 KB
  __shared__ float Bs[BK][BN];         // 2 KB
  const int m0 = blockIdx.x * BM;
  const int n0 = blockIdx.y * BN;
  const int t  = threadIdx.x;

  // hot-loop mapping: 16 row-groups x 8 col-groups
  const int tm = t / 8;        // 0..15 -> rows tm*8 .. +7
  const int tn = t % 8;        // 0..7  -> cols tn*4 .. +3

  // A staging: 4 rows x 4 k-bytes per thread, byte-transposed via v_perm
  const int ar0 = (t % 32) * 4;   // row base 0..124
  const int ak0 = (t / 32) * 4;   // k base 0,4,8,12

  // B staging: 1 row x 4 k per thread (float4)
  const int brow = t % 32;
  const int bk0  = (t / 32) * 4;

  float acc[8][4] = {};    // current panel chain
  float tot[8][4];         // committed C (valid after first commit)

  for (int k0 = 0; k0 < KIN; k0 += BK) {
    // ---- stage A: load 4 rows' u32 (4 bytes each), 4x4 byte-transpose ----
    {
      uint32_t r0 = *(const uint32_t*)(enc + (size_t)(m0 + ar0 + 0) * KIN + k0 + ak0);
      uint32_t r1 = *(const uint32_t*)(enc + (size_t)(m0 + ar0 + 1) * KIN + k0 + ak0);
      uint32_t r2 = *(const uint32_t*)(enc + (size_t)(m0 + ar0 + 2) * KIN + k0 + ak0);
      uint32_t r3 = *(const uint32_t*)(enc + (size_t)(m0 + ar0 + 3) * KIN + k0 + ak0);
      // interleave pairs: (r0[j], r1[j], ...)
      uint32_t a01  = __builtin_amdgcn_perm(r1, r0, 0x05010400u); // r0[0] r1[0] r0[1] r1[1]
      uint32_t a01h = __builtin_amdgcn_perm(r1, r0, 0x07030602u); // r0[2] r1[2] r0[3] r1[3]
      uint32_t a23  = __builtin_amdgcn_perm(r3, r2, 0x05010400u);
      uint32_t a23h = __builtin_amdgcn_perm(r3, r2, 0x07030602u);
      As[ak0 + 0][ar0 >> 2] = __builtin_amdgcn_perm(a23,  a01,  0x05040100u); // col j=0: rows 0..3
      As[ak0 + 1][ar0 >> 2] = __builtin_amdgcn_perm(a23,  a01,  0x07060302u);
      As[ak0 + 2][ar0 >> 2] = __builtin_amdgcn_perm(a23h, a01h, 0x05040100u);
      As[ak0 + 3][ar0 >> 2] = __builtin_amdgcn_perm(a23h, a01h, 0x07060302u);
    }
    // ---- stage B: 32 rows x 16 k ----
    {
      const float* src = w1 + (size_t)(n0 + brow) * KIN + k0 + bk0;
      float4 v = *(const float4*)src;
      Bs[bk0 + 0][brow] = v.x;
      Bs[bk0 + 1][brow] = v.y;
      Bs[bk0 + 2][brow] = v.z;
      Bs[bk0 + 3][brow] = v.w;
    }
    __syncthreads();
#pragma unroll
    for (int kk = 0; kk < BK; kk++) {
      const int kglob = k0 + kk;
      if (kglob == PANEL1) {
#pragma unroll
        for (int mi = 0; mi < 8; mi++)
#pragma unroll
          for (int ni = 0; ni < 4; ni++) { tot[mi][ni] = acc[mi][ni]; acc[mi][ni] = 0.0f; }
      } else if (kglob == PANEL2) {
#pragma unroll
        for (int mi = 0; mi < 8; mi++)
#pragma unroll
          for (int ni = 0; ni < 4; ni++) { tot[mi][ni] = __fadd_rn(tot[mi][ni], acc[mi][ni]); acc[mi][ni] = 0.0f; }
      }
      // A fragment: 8 u8 rows (2 packed words), convert in-register
      uint2 av = *(const uint2*)&As[kk][tm * 2];
      float a[8];
      a[0] = cvt_ub(av.x, 0);
      a[1] = cvt_ub(av.x, 1);
      a[2] = cvt_ub(av.x, 2);
      a[3] = cvt_ub(av.x, 3);
      a[4] = cvt_ub(av.y, 0);
      a[5] = cvt_ub(av.y, 1);
      a[6] = cvt_ub(av.y, 2);
      a[7] = cvt_ub(av.y, 3);
      // B fragment: 4 f32
      float4 bv = *(const float4*)&Bs[kk][tn * 4];
      float b[4] = {bv.x, bv.y, bv.z, bv.w};
#pragma unroll
      for (int mi = 0; mi < 8; mi++)
#pragma unroll
        for (int ni = 0; ni < 4; ni++)
          acc[mi][ni] = __builtin_fmaf(a[mi], b[ni], acc[mi][ni]);  // exact product => == mul+add
    }
    __syncthreads();
  }
#pragma unroll
  for (int mi = 0; mi < 8; mi++) {
    float* dst = g + (size_t)(m0 + tm * 8 + mi) * HID + n0 + tn * 4;
    float4 o;
    o.x = __fmul_rn(0.5f, __fadd_rn(tot[mi][0], acc[mi][0]));  // (P0+P1)+P2, exact 0.5
    o.y = __fmul_rn(0.5f, __fadd_rn(tot[mi][1], acc[mi][1]));
    o.z = __fmul_rn(0.5f, __fadd_rn(tot[mi][2], acc[mi][2]));
    o.w = __fmul_rn(0.5f, __fadd_rn(tot[mi][3], acc[mi][3]));
    *(float4*)dst = o;
  }
}

// ---------------------------------------------------------------------------
// Kernel 3: f32 membrane update + spike + mem2 accumulation.
// m = rn(rn(0.95f*mem) + rn(0.05f*g)) — mul/mul/add; products NOT exact here,
// so FMA contraction would change bits — keep split __fmul_rn/__fadd_rn.
// ---------------------------------------------------------------------------
__global__ __launch_bounds__(256) void update_kernel(const float* __restrict__ g,
                                                     float* __restrict__ mem1,
                                                     const float* __restrict__ w2,
                                                     float* __restrict__ mem2) {
  __shared__ float w2s[NOUT * HID];   // 32 KB
  for (int i = threadIdx.x; i < NOUT * HID; i += 256) w2s[i] = w2[i];
  __syncthreads();

  const int wave = threadIdx.x / 64;
  const int lane = threadIdx.x % 64;
  const int b = blockIdx.x * 4 + wave;

  const float* grow = g + (size_t)b * HID;
  float* mrow = mem1 + (size_t)b * HID;

  float acc[NOUT];
#pragma unroll
  for (int i = 0; i < NOUT; i++) acc[i] = 0.0f;

  for (int j = lane; j < HID; j += 64) {
    float m = __fadd_rn(__fmul_rn(0.95f, mrow[j]), __fmul_rn(0.05f, grow[j]));
    bool spike = __fadd_rn(m, -1.0f) > 0.0f;
    mrow[j] = spike ? __fadd_rn(m, -1.0f) : m;
    if (spike) {
#pragma unroll
      for (int i = 0; i < NOUT; i++) acc[i] += w2s[i * HID + j];
    }
  }
  // mem2 never feeds back into spike decisions: reduction-order noise ~1e-7
  // << 3.6e-3 threshold, no need to replicate ref's order here.
#pragma unroll
  for (int i = 0; i < NOUT; i++) {
    float v = acc[i];
    for (int off = 32; off > 0; off >>= 1) v += __shfl_down(v, off);
    if (lane == 0) mem2[(size_t)b * NOUT + i] += v;
  }
}

// ---------------------------------------------------------------------------
// Kernel 4: out = mem2 / num_steps
// ---------------------------------------------------------------------------
__global__ __launch_bounds__(256) void finalize_kernel(const float* __restrict__ mem2,
                                                       const int* __restrict__ ns,
                                                       float* __restrict__ out) {
  int i = blockIdx.x * blockDim.x + threadIdx.x;
  if (i < BSZ * NOUT) out[i] = mem2[i] / (float)(*ns);
}

// ---------------------------------------------------------------------------
extern "C" void kernel_launch(void* const* d_in, const int* in_sizes, int n_in,
                              void* d_out, int out_size, void* d_ws, size_t ws_size,
                              hipStream_t stream) {
  const float* inp = (const float*)d_in[0];
  const float* w1  = (const float*)d_in[1];
  const float* w2  = (const float*)d_in[2];
  const int*   dns = (const int*)d_in[3];
  float* out = (float*)d_out;

  char* ws = (char*)d_ws;
  size_t off = 0;
  uint8_t* enc = (uint8_t*)(ws + off);  off += (size_t)BSZ * KIN;          // 6.4 MB
  off = (off + 255) & ~(size_t)255;
  float* g    = (float*)(ws + off);     off += (size_t)BSZ * HID * 4;      // 26.2 MB
  float* mem1 = (float*)(ws + off);     off += (size_t)BSZ * HID * 4;      // 26.2 MB
  float* mem2 = (float*)(ws + off);     off += (size_t)BSZ * NOUT * 4;     // 0.33 MB

  (void)hipMemsetAsync(mem1, 0, (size_t)BSZ * HID * 4, stream);
  (void)hipMemsetAsync(mem2, 0, (size_t)BSZ * NOUT * 4, stream);

  // Step keys: partitionable split — key_t = threefry((0,42), (0,t)).
  uint32_t keys[NSTEP][2];
  for (int t = 0; t < NSTEP; t++)
    threefry2x32(0u, 42u, 0u, (uint32_t)t, &keys[t][0], &keys[t][1]);

  const int n_elem = BSZ * KIN;
  for (int t = 0; t < NSTEP; t++) {
    enc_kernel<<<(n_elem + 255) / 256, 256, 0, stream>>>(inp, enc, keys[t][0], keys[t][1]);
    gemm_kernel<<<dim3(BSZ / BM, HID / BN), 128, 0, stream>>>(enc, w1, g);
    update_kernel<<<BSZ / 4, 256, 0, stream>>>(g, mem1, w2, mem2);
  }
  finalize_kernel<<<(BSZ * NOUT + 255) / 256, 256, 0, stream>>>(mem2, dns, out);
}